// Round 10
// baseline (78.431 us; speedup 1.0000x reference)
//
#include <hip/hip_runtime.h>
#include <hip/hip_bf16.h>

#define NB 8
#define SS 2048
#define DD 128
#define NQK (NB * SS * DD)

typedef __attribute__((ext_vector_type(8))) short bf16x8;
typedef __attribute__((ext_vector_type(16))) float f32x16;
typedef __attribute__((ext_vector_type(4))) float f32x4;
typedef __attribute__((ext_vector_type(4))) unsigned int uint4v;
typedef __attribute__((ext_vector_type(2))) unsigned int uint2v;

static constexpr float C1 = 0.08838834764831845f * 1.4426950408889634f;  // SCALE*log2(e)

#define MFMA32(a, b, c) __builtin_amdgcn_mfma_f32_32x32x16_bf16(a, b, c, 0, 0, 0)
#define PSWAP(a, b) __builtin_amdgcn_permlane32_swap(a, b, false, false)

#if __has_builtin(__builtin_amdgcn_exp2f)
#define EXP2 __builtin_amdgcn_exp2f
#else
#define EXP2 exp2f
#endif

__device__ __forceinline__ unsigned short f2bf(float x) {
  __hip_bfloat16 h = __float2bfloat16(x);  // RNE
  unsigned short r;
  __builtin_memcpy(&r, &h, 2);
  return r;
}

__device__ __forceinline__ void nt_store4(const float* src, float* dst) {
  f32x4 v;
  __builtin_memcpy(&v, src, 16);
  __builtin_nontemporal_store(v, (f32x4*)dst);
}

// ---------------------------------------------------------------------------
// prep: fp32 -> bf16 fragment-tiled layouts (unchanged).
// ---------------------------------------------------------------------------
__global__ __launch_bounds__(256)
void prep_kernel(const float* __restrict__ Q, const float* __restrict__ K,
                 const float* __restrict__ V, unsigned short* __restrict__ Qt,
                 unsigned short* __restrict__ Kt, unsigned short* __restrict__ Vt) {
  __shared__ __align__(16) float Tf[32][132];
  const int ti = blockIdx.x, b = blockIdx.y, role = blockIdx.z;
  const int tid = threadIdx.x;
  const float* src = role == 0 ? Q : (role == 1 ? K : V);
  {
    const int row = tid >> 3, seg = (tid & 7) * 16;
    const float4* sp = (const float4*)(src + ((size_t)b * SS + ti * 32 + row) * DD + seg);
#pragma unroll
    for (int j = 0; j < 4; ++j) *(float4*)&Tf[row][seg + 4 * j] = sp[j];
  }
  __syncthreads();
  if (role < 2) {
    unsigned short* dst = (role == 0 ? Qt : Kt) + ((size_t)b * 64 + ti) * 4096;
#pragma unroll
    for (int e = 0; e < 2; ++e) {
      const int c = 2 * tid + e, lq = c & 31, ck = c >> 5;
      const float4 a = *(const float4*)&Tf[lq][ck * 8];
      const float4 d = *(const float4*)&Tf[lq][ck * 8 + 4];
      bf16x8 o;
      o[0] = (short)f2bf(a.x); o[1] = (short)f2bf(a.y);
      o[2] = (short)f2bf(a.z); o[3] = (short)f2bf(a.w);
      o[4] = (short)f2bf(d.x); o[5] = (short)f2bf(d.y);
      o[6] = (short)f2bf(d.z); o[7] = (short)f2bf(d.w);
      *(bf16x8*)(dst + c * 8) = o;
    }
  } else {
    unsigned short* dst = Vt + ((size_t)b * 64 + ti) * 4096;
#pragma unroll
    for (int e = 0; e < 2; ++e) {
      const int chunk = 2 * tid + e, cc = chunk >> 7, d = chunk & 127;
      bf16x8 o;
#pragma unroll
      for (int j = 0; j < 8; ++j) o[j] = (short)f2bf(Tf[cc * 8 + j][d]);
      *(bf16x8*)(dst + chunk * 8) = o;
    }
  }
}

// ---------------------------------------------------------------------------
// attn: Phase A stats + Phase B with 4-tile LDS-accumulated W stores:
// P tiles for 4 consecutive 32-col tiles accumulate in PW[wv][32][132];
// every 4th iteration a flush writes 16 x (2 rows x 512 B contiguous)
// nontemporal dwordx4 stores (4x longer HBM bursts than per-tile stores).
// R (O-reduction) aliases PW after a barrier. grid 512, block 256.
// ---------------------------------------------------------------------------
__global__ __launch_bounds__(256, 2)
void attn_kernel(const unsigned short* __restrict__ Qt,
                 const unsigned short* __restrict__ Kt,
                 const unsigned short* __restrict__ Vt,
                 float* __restrict__ W, float* __restrict__ Out) {
  __shared__ __align__(16) float PW[4][32][132];  // per-wave 4-tile P buffer
  __shared__ float2 sms[4][32];
  float (*R)[132] = (float(*)[132]) & PW[0][0][0];  // epilogue alias

  const int bid = blockIdx.x;
  const int b = bid & 7, qb = bid >> 3;  // XCD-batch swizzle
  const int q0 = qb * 32;
  const int tid = threadIdx.x;
  const int lane = tid & 63, wv = tid >> 6;
  const int lq = lane & 31, h2 = lane >> 5;
  const int stag4 = ((qb + wv) & 3) * 4;  // 4-tile-aligned stagger
  const f32x16 ZERO16 = {0, 0, 0, 0, 0, 0, 0, 0, 0, 0, 0, 0, 0, 0, 0, 0};

  const unsigned short* qbase = Qt + ((size_t)b * 64 + (q0 >> 5)) * 4096;
  bf16x8 qh[8];
#pragma unroll
  for (int ds = 0; ds < 8; ++ds)
    qh[ds] = *(const bf16x8*)(qbase + ((ds * 2 + h2) * 32 + lq) * 8);

  const unsigned short* const ktw = Kt + ((size_t)b * 64 + wv * 16) * 4096;
  const unsigned short* const vtw = Vt + ((size_t)b * 64 + wv * 16) * 4096;

  // ================= Phase A: stats over this wave's 512 keys =============
  float m2 = -1e30f, s2 = 0.f;
#pragma unroll
  for (int kp = 0; kp < 8; ++kp) {
    const unsigned short* kb0 = ktw + (2 * kp) * 4096;
    const unsigned short* kb1 = kb0 + 4096;
    bf16x8 a0[8], a1[8];
#pragma unroll
    for (int ds = 0; ds < 8; ++ds) {
      a0[ds] = *(const bf16x8*)(kb0 + ((ds * 2 + h2) * 32 + lq) * 8);
      a1[ds] = *(const bf16x8*)(kb1 + ((ds * 2 + h2) * 32 + lq) * 8);
    }
    f32x16 acc0 = ZERO16, acc1 = ZERO16;
#pragma unroll
    for (int ds = 0; ds < 8; ++ds) {
      acc0 = MFMA32(a0[ds], qh[ds], acc0);
      acc1 = MFMA32(a1[ds], qh[ds], acc1);
    }
    float tm0 = acc0[0], tm1 = acc1[0];
#pragma unroll
    for (int r = 1; r < 16; ++r) {
      tm0 = fmaxf(tm0, acc0[r]);
      tm1 = fmaxf(tm1, acc1[r]);
    }
    const float nm2 = fmaxf(m2, fmaxf(tm0, tm1) * C1);
    float add = 0.f;
#pragma unroll
    for (int r = 0; r < 16; ++r)
      add += EXP2(fmaf(acc0[r], C1, -nm2)) + EXP2(fmaf(acc1[r], C1, -nm2));
    s2 = s2 * EXP2(m2 - nm2) + add;
    m2 = nm2;
  }
  {
    const float mo = __shfl_xor(m2, 32);
    const float so = __shfl_xor(s2, 32);
    const float nm = fmaxf(m2, mo);
    s2 = s2 * EXP2(m2 - nm) + so * EXP2(mo - nm);
    if (h2 == 0) sms[wv][lq] = make_float2(nm, s2);
  }
  __syncthreads();
  float lb;
  {
    float2 pj[4];
    float m = -1e30f;
#pragma unroll
    for (int j = 0; j < 4; ++j) {
      pj[j] = sms[j][lq];
      m = fmaxf(m, pj[j].x);
    }
    float s = 0.f;
#pragma unroll
    for (int j = 0; j < 4; ++j) s += pj[j].y * EXP2(pj[j].x - m);
    lb = -(m + __log2f(s));
  }

  // ================= Phase B: normalize + buffered W + PV =================
  f32x16 accO[4];
#pragma unroll
  for (int dt = 0; dt < 4; ++dt) accO[dt] = ZERO16;

  // pipeline prologue: QK + V-frag loads for first (staggered) tile
  f32x16 acc = ZERO16;
  bf16x8 vb[8];
  {
    const unsigned short* k0 = ktw + stag4 * 4096;
    const unsigned short* v0 = vtw + stag4 * 4096;
    bf16x8 ah[8];
#pragma unroll
    for (int ds = 0; ds < 8; ++ds)
      ah[ds] = *(const bf16x8*)(k0 + ((ds * 2 + h2) * 32 + lq) * 8);
#pragma unroll
    for (int ds = 0; ds < 8; ++ds) acc = MFMA32(ah[ds], qh[ds], acc);
#pragma unroll
    for (int kk = 0; kk < 2; ++kk)
#pragma unroll
      for (int dt = 0; dt < 4; ++dt)
        vb[kk * 4 + dt] =
            *(const bf16x8*)(v0 + ((kk * 2 + h2) * 128 + dt * 32 + lq) * 8);
  }

  // per-lane flush constants: fp = col-block, fc = col within block
  const int fp = lq >> 3, fc = (lq & 7) * 4;
  float* const wq0 = W + ((size_t)b * SS + q0) * SS + wv * 512;

  for (int kt = 0; kt < 16; ++kt) {
    const int lt = (kt + stag4) & 15;  // staggered tile (groups of 4 aligned)
    const int p = kt & 3;              // slot within the 4-tile buffer
    // ---- prefetch next tile's K and V fragments ----
    bf16x8 ahn[8], vbn[8];
    if (kt < 15) {
      const int ln = (kt + 1 + stag4) & 15;
      const unsigned short* kn = ktw + ln * 4096;
      const unsigned short* vn = vtw + ln * 4096;
#pragma unroll
      for (int ds = 0; ds < 8; ++ds)
        ahn[ds] = *(const bf16x8*)(kn + ((ds * 2 + h2) * 32 + lq) * 8);
#pragma unroll
      for (int kk = 0; kk < 2; ++kk)
#pragma unroll
        for (int dt = 0; dt < 4; ++dt)
          vbn[kk * 4 + dt] =
              *(const bf16x8*)(vn + ((kk * 2 + h2) * 128 + dt * 32 + lq) * 8);
    }
    // ---- softmax: p4 = exp2(s*C1 + lb); buffer into PW; bf16 pack ----
    // D layout: col(q)=lq, key row = (r&3) + 8*(r>>2) + 4*h2
    unsigned int U[8];
    {
      float* pwr = &PW[wv][lq][p * 32];
#pragma unroll
      for (int g = 0; g < 4; ++g) {
        const float p0 = EXP2(fmaf(acc[4 * g + 0], C1, lb));
        const float p1 = EXP2(fmaf(acc[4 * g + 1], C1, lb));
        const float p2 = EXP2(fmaf(acc[4 * g + 2], C1, lb));
        const float p3 = EXP2(fmaf(acc[4 * g + 3], C1, lb));
        *(float4*)(pwr + ((8 * g + 4 * h2 + 4 * lq + 8 * p) & 31)) =
            make_float4(p0, p1, p2, p3);
        U[2 * g] = (unsigned)f2bf(p0) | ((unsigned)f2bf(p1) << 16);
        U[2 * g + 1] = (unsigned)f2bf(p2) | ((unsigned)f2bf(p3) << 16);
      }
    }
    // ---- next tile's QK (independent; hides LDS write latency) ----
    f32x16 accn = ZERO16;
    if (kt < 15) {
#pragma unroll
      for (int ds = 0; ds < 8; ++ds) accn = MFMA32(ahn[ds], qh[ds], accn);
    }
    // ---- flush: every 4th tile, write 128-col window, 512 B/row bursts ----
    if (p == 3) {
      asm volatile("" ::: "memory");  // keep LDS writes above the reads
      const int gb = ((kt & ~3) + stag4) & 15;  // group base tile
      float* wcol = wq0 + (gb + fp) * 32 + fc;
#pragma unroll
      for (int ii = 0; ii < 16; ++ii) {
        const int row = 2 * ii + h2;
        nt_store4(&PW[wv][row][fp * 32 + ((fc + 4 * row + 8 * fp) & 31)],
                  wcol + (size_t)row * SS);
      }
    }
    // ---- P redistribution via permlane32_swap (lane l <-> l+32) ----
    const uint2v s02 = PSWAP(U[0], U[2]);
    const uint2v s13 = PSWAP(U[1], U[3]);
    const uint2v s46 = PSWAP(U[4], U[6]);
    const uint2v s57 = PSWAP(U[5], U[7]);
    uint4v w0, w1;
    w0.x = s02.x; w0.y = s13.x; w0.z = s02.y; w0.w = s13.y;
    w1.x = s46.x; w1.y = s57.x; w1.z = s46.y; w1.w = s57.y;
    const bf16x8 pa0 = __builtin_bit_cast(bf16x8, w0);
    const bf16x8 pa1 = __builtin_bit_cast(bf16x8, w1);
    // ---- PV (V-frags prefetched last iter) ----
#pragma unroll
    for (int dt = 0; dt < 4; ++dt) accO[dt] = MFMA32(pa0, vb[dt], accO[dt]);
#pragma unroll
    for (int dt = 0; dt < 4; ++dt) accO[dt] = MFMA32(pa1, vb[4 + dt], accO[dt]);
    acc = accn;
#pragma unroll
    for (int j = 0; j < 8; ++j) vb[j] = vbn[j];
  }

  // ---- 4-way O reduction in LDS (R aliases PW; all flushes done) ----
  __syncthreads();
#pragma unroll
  for (int ph = 0; ph < 4; ++ph) {
    if (wv == ph) {
#pragma unroll
      for (int dt = 0; dt < 4; ++dt) {
#pragma unroll
        for (int r = 0; r < 16; ++r) {
          const int q = (r & 3) + 8 * (r >> 2) + 4 * h2;
          if (ph == 0) R[q][dt * 32 + lq] = accO[dt][r];
          else         R[q][dt * 32 + lq] += accO[dt][r];
        }
      }
    }
    __syncthreads();
  }
  {
    const int row = tid >> 3, c0 = (tid & 7) * 16;
    float* ob = Out + ((size_t)b * SS + q0 + row) * DD + c0;
#pragma unroll
    for (int j = 0; j < 4; ++j) nt_store4(&R[row][c0 + 4 * j], ob + 4 * j);
  }
}

// ---------------------------------------------------------------------------
extern "C" void kernel_launch(void* const* d_in, const int* in_sizes, int n_in,
                              void* d_out, int out_size, void* d_ws, size_t ws_size,
                              hipStream_t stream) {
  const float* Q = (const float*)d_in[0];
  const float* K = (const float*)d_in[1];
  const float* V = (const float*)d_in[2];
  float* out = (float*)d_out;
  float* W = out + (size_t)NQK;  // attn_weights region of d_out

  char* ws = (char*)d_ws;  // 12 MB used
  unsigned short* Qt = (unsigned short*)(ws);
  unsigned short* Kt = (unsigned short*)(ws + ((size_t)4 << 20));
  unsigned short* Vt = (unsigned short*)(ws + ((size_t)8 << 20));

  prep_kernel<<<dim3(64, 8, 3), 256, 0, stream>>>(Q, K, V, Qt, Kt, Vt);
  attn_kernel<<<512, 256, 0, stream>>>(Qt, Kt, Vt, W, out);
}

// Round 11
// 62.906 us; speedup vs baseline: 1.2468x; 1.2468x over previous
//
#include <hip/hip_runtime.h>
#include <hip/hip_bf16.h>

#define NB 8
#define SS 2048
#define DD 128
#define NQK (NB * SS * DD)

typedef __attribute__((ext_vector_type(8))) short bf16x8;
typedef __attribute__((ext_vector_type(16))) float f32x16;
typedef __attribute__((ext_vector_type(4))) float f32x4;
typedef __attribute__((ext_vector_type(4))) unsigned int uint4v;
typedef __attribute__((ext_vector_type(2))) unsigned int uint2v;

static constexpr float C1 = 0.08838834764831845f * 1.4426950408889634f;  // SCALE*log2(e)

#define MFMA32(a, b, c) __builtin_amdgcn_mfma_f32_32x32x16_bf16(a, b, c, 0, 0, 0)
#define PSWAP(a, b) __builtin_amdgcn_permlane32_swap(a, b, false, false)

#if __has_builtin(__builtin_amdgcn_exp2f)
#define EXP2 __builtin_amdgcn_exp2f
#else
#define EXP2 exp2f
#endif

__device__ __forceinline__ unsigned short f2bf(float x) {
  __hip_bfloat16 h = __float2bfloat16(x);  // RNE
  unsigned short r;
  __builtin_memcpy(&r, &h, 2);
  return r;
}

// plain store (acks from L2 quickly; nt variant acked too slowly and, with
// in-order vmcnt, serialized every iteration on HBM write latency)
__device__ __forceinline__ void st4(const float* src, float* dst) {
  f32x4 v;
  __builtin_memcpy(&v, src, 16);
  *(f32x4*)dst = v;
}

__device__ __forceinline__ void nt_store4(const float* src, float* dst) {
  f32x4 v;
  __builtin_memcpy(&v, src, 16);
  __builtin_nontemporal_store(v, (f32x4*)dst);
}

// ---------------------------------------------------------------------------
// prep: fp32 -> bf16 fragment-tiled layouts (unchanged).
// ---------------------------------------------------------------------------
__global__ __launch_bounds__(256)
void prep_kernel(const float* __restrict__ Q, const float* __restrict__ K,
                 const float* __restrict__ V, unsigned short* __restrict__ Qt,
                 unsigned short* __restrict__ Kt, unsigned short* __restrict__ Vt) {
  __shared__ __align__(16) float Tf[32][132];
  const int ti = blockIdx.x, b = blockIdx.y, role = blockIdx.z;
  const int tid = threadIdx.x;
  const float* src = role == 0 ? Q : (role == 1 ? K : V);
  {
    const int row = tid >> 3, seg = (tid & 7) * 16;
    const float4* sp = (const float4*)(src + ((size_t)b * SS + ti * 32 + row) * DD + seg);
#pragma unroll
    for (int j = 0; j < 4; ++j) *(float4*)&Tf[row][seg + 4 * j] = sp[j];
  }
  __syncthreads();
  if (role < 2) {
    unsigned short* dst = (role == 0 ? Qt : Kt) + ((size_t)b * 64 + ti) * 4096;
#pragma unroll
    for (int e = 0; e < 2; ++e) {
      const int c = 2 * tid + e, lq = c & 31, ck = c >> 5;
      const float4 a = *(const float4*)&Tf[lq][ck * 8];
      const float4 d = *(const float4*)&Tf[lq][ck * 8 + 4];
      bf16x8 o;
      o[0] = (short)f2bf(a.x); o[1] = (short)f2bf(a.y);
      o[2] = (short)f2bf(a.z); o[3] = (short)f2bf(a.w);
      o[4] = (short)f2bf(d.x); o[5] = (short)f2bf(d.y);
      o[6] = (short)f2bf(d.z); o[7] = (short)f2bf(d.w);
      *(bf16x8*)(dst + c * 8) = o;
    }
  } else {
    unsigned short* dst = Vt + ((size_t)b * 64 + ti) * 4096;
#pragma unroll
    for (int e = 0; e < 2; ++e) {
      const int chunk = 2 * tid + e, cc = chunk >> 7, d = chunk & 127;
      bf16x8 o;
#pragma unroll
      for (int j = 0; j < 8; ++j) o[j] = (short)f2bf(Tf[cc * 8 + j][d]);
      *(bf16x8*)(dst + chunk * 8) = o;
    }
  }
}

// ---------------------------------------------------------------------------
// attn: single fused kernel (round-9 structure; W stores NOT nontemporal).
// Phase A: per-wave QK over its 512-key slice, online stats, 4-wave reduce.
// Phase B: QK recompute (pipelined 1 tile ahead), W = exp2(fma(s,C1,lb)) via
// per-wave LDS gather + plain full-line stores, permlane P redistribution,
// PV MFMA with V-frags prefetched one tile ahead.
// grid 512 linear (b = id&7 XCD-batch swizzle), block 256 = 4 waves.
// ---------------------------------------------------------------------------
__global__ __launch_bounds__(256, 2)
void attn_kernel(const unsigned short* __restrict__ Qt,
                 const unsigned short* __restrict__ Kt,
                 const unsigned short* __restrict__ Vt,
                 float* __restrict__ W, float* __restrict__ Out) {
  __shared__ __align__(16) float PW[4][32][40];  // per-wave P gather, rotated cols
  __shared__ __align__(16) float R[32][132];
  __shared__ float2 sms[4][32];

  const int bid = blockIdx.x;
  const int b = bid & 7, qb = bid >> 3;  // XCD-batch swizzle
  const int q0 = qb * 32;
  const int tid = threadIdx.x;
  const int lane = tid & 63, wv = tid >> 6;
  const int lq = lane & 31, h2 = lane >> 5;
  const int stag = (4 * qb + wv) & 15;  // store channel-phase stagger
  const f32x16 ZERO16 = {0, 0, 0, 0, 0, 0, 0, 0, 0, 0, 0, 0, 0, 0, 0, 0};

  {
    float* Rf = &R[0][0];
    for (int idx = tid; idx < 32 * 132; idx += 256) Rf[idx] = 0.f;
  }

  const unsigned short* qbase = Qt + ((size_t)b * 64 + (q0 >> 5)) * 4096;
  bf16x8 qh[8];
#pragma unroll
  for (int ds = 0; ds < 8; ++ds)
    qh[ds] = *(const bf16x8*)(qbase + ((ds * 2 + h2) * 32 + lq) * 8);

  const unsigned short* const ktw = Kt + ((size_t)b * 64 + wv * 16) * 4096;
  const unsigned short* const vtw = Vt + ((size_t)b * 64 + wv * 16) * 4096;

  // ================= Phase A: stats over this wave's 512 keys =============
  float m2 = -1e30f, s2 = 0.f;
#pragma unroll
  for (int kp = 0; kp < 8; ++kp) {
    const unsigned short* kb0 = ktw + (2 * kp) * 4096;
    const unsigned short* kb1 = kb0 + 4096;
    bf16x8 a0[8], a1[8];
#pragma unroll
    for (int ds = 0; ds < 8; ++ds) {
      a0[ds] = *(const bf16x8*)(kb0 + ((ds * 2 + h2) * 32 + lq) * 8);
      a1[ds] = *(const bf16x8*)(kb1 + ((ds * 2 + h2) * 32 + lq) * 8);
    }
    f32x16 acc0 = ZERO16, acc1 = ZERO16;
#pragma unroll
    for (int ds = 0; ds < 8; ++ds) {
      acc0 = MFMA32(a0[ds], qh[ds], acc0);
      acc1 = MFMA32(a1[ds], qh[ds], acc1);
    }
    float tm0 = acc0[0], tm1 = acc1[0];
#pragma unroll
    for (int r = 1; r < 16; ++r) {
      tm0 = fmaxf(tm0, acc0[r]);
      tm1 = fmaxf(tm1, acc1[r]);
    }
    const float nm2 = fmaxf(m2, fmaxf(tm0, tm1) * C1);
    float add = 0.f;
#pragma unroll
    for (int r = 0; r < 16; ++r)
      add += EXP2(fmaf(acc0[r], C1, -nm2)) + EXP2(fmaf(acc1[r], C1, -nm2));
    s2 = s2 * EXP2(m2 - nm2) + add;
    m2 = nm2;
  }
  {
    const float mo = __shfl_xor(m2, 32);
    const float so = __shfl_xor(s2, 32);
    const float nm = fmaxf(m2, mo);
    s2 = s2 * EXP2(m2 - nm) + so * EXP2(mo - nm);
    if (h2 == 0) sms[wv][lq] = make_float2(nm, s2);
  }
  __syncthreads();
  float lb;
  {
    float2 pj[4];
    float m = -1e30f;
#pragma unroll
    for (int j = 0; j < 4; ++j) {
      pj[j] = sms[j][lq];
      m = fmaxf(m, pj[j].x);
    }
    float s = 0.f;
#pragma unroll
    for (int j = 0; j < 4; ++j) s += pj[j].y * EXP2(pj[j].x - m);
    lb = -(m + __log2f(s));
  }

  // ================= Phase B: normalize + W + PV ==========================
  float* pwwr[4];
#pragma unroll
  for (int g = 0; g < 4; ++g)
    pwwr[g] = &PW[wv][lq][(8 * g + 4 * h2 + lq * 4) & 31];
  const int gq8 = lane >> 3, gks = lane & 7;
  const float* pwrd[4];
  float* wgb[4];
#pragma unroll
  for (int i = 0; i < 4; ++i) {
    const int row = i * 8 + gq8;
    pwrd[i] = &PW[wv][row][(gks * 4 + row * 4) & 31];
    wgb[i] = W + ((size_t)b * SS + q0 + row) * SS + gks * 4;
  }

  f32x16 accO[4];
#pragma unroll
  for (int dt = 0; dt < 4; ++dt) accO[dt] = ZERO16;

  // pipeline prologue: QK + V-frag loads for first (staggered) tile
  f32x16 acc = ZERO16;
  bf16x8 vb[8];
  {
    const unsigned short* k0 = ktw + stag * 4096;
    const unsigned short* v0 = vtw + stag * 4096;
    bf16x8 ah[8];
#pragma unroll
    for (int ds = 0; ds < 8; ++ds)
      ah[ds] = *(const bf16x8*)(k0 + ((ds * 2 + h2) * 32 + lq) * 8);
#pragma unroll
    for (int ds = 0; ds < 8; ++ds) acc = MFMA32(ah[ds], qh[ds], acc);
#pragma unroll
    for (int kk = 0; kk < 2; ++kk)
#pragma unroll
      for (int dt = 0; dt < 4; ++dt)
        vb[kk * 4 + dt] =
            *(const bf16x8*)(v0 + ((kk * 2 + h2) * 128 + dt * 32 + lq) * 8);
  }

  for (int kt = 0; kt < 16; ++kt) {
    const int lt = (kt + stag) & 15;            // this wave's staggered tile
    const int kb = (wv * 16 + lt) * 32;
    // ---- prefetch next tile's K and V fragments ----
    bf16x8 ahn[8], vbn[8];
    if (kt < 15) {
      const int ln = (kt + 1 + stag) & 15;
      const unsigned short* kn = ktw + ln * 4096;
      const unsigned short* vn = vtw + ln * 4096;
#pragma unroll
      for (int ds = 0; ds < 8; ++ds)
        ahn[ds] = *(const bf16x8*)(kn + ((ds * 2 + h2) * 32 + lq) * 8);
#pragma unroll
      for (int kk = 0; kk < 2; ++kk)
#pragma unroll
        for (int dt = 0; dt < 4; ++dt)
          vbn[kk * 4 + dt] =
              *(const bf16x8*)(vn + ((kk * 2 + h2) * 128 + dt * 32 + lq) * 8);
    }
    // ---- softmax: p = exp2(s*C1 + lb); LDS gather write; bf16 pack ----
    // D layout: col(q)=lq, key row = (r&3) + 8*(r>>2) + 4*h2
    unsigned int U[8];
#pragma unroll
    for (int g = 0; g < 4; ++g) {
      const float p0 = EXP2(fmaf(acc[4 * g + 0], C1, lb));
      const float p1 = EXP2(fmaf(acc[4 * g + 1], C1, lb));
      const float p2 = EXP2(fmaf(acc[4 * g + 2], C1, lb));
      const float p3 = EXP2(fmaf(acc[4 * g + 3], C1, lb));
      *(float4*)pwwr[g] = make_float4(p0, p1, p2, p3);
      U[2 * g] = (unsigned)f2bf(p0) | ((unsigned)f2bf(p1) << 16);
      U[2 * g + 1] = (unsigned)f2bf(p2) | ((unsigned)f2bf(p3) << 16);
    }
    // ---- next tile's QK (independent; hides LDS write latency) ----
    f32x16 accn = ZERO16;
    if (kt < 15) {
#pragma unroll
      for (int ds = 0; ds < 8; ++ds) accn = MFMA32(ahn[ds], qh[ds], accn);
    }
    // ---- gathered W stores (full-line segments; plain, L2-acked) ----
#pragma unroll
    for (int i = 0; i < 4; ++i) st4(pwrd[i], wgb[i] + kb);
    // ---- P redistribution via permlane32_swap (lane l <-> l+32) ----
    const uint2v s02 = PSWAP(U[0], U[2]);
    const uint2v s13 = PSWAP(U[1], U[3]);
    const uint2v s46 = PSWAP(U[4], U[6]);
    const uint2v s57 = PSWAP(U[5], U[7]);
    uint4v w0, w1;
    w0.x = s02.x; w0.y = s13.x; w0.z = s02.y; w0.w = s13.y;
    w1.x = s46.x; w1.y = s57.x; w1.z = s46.y; w1.w = s57.y;
    const bf16x8 pa0 = __builtin_bit_cast(bf16x8, w0);
    const bf16x8 pa1 = __builtin_bit_cast(bf16x8, w1);
    // ---- PV (V-frags prefetched last iter) ----
#pragma unroll
    for (int dt = 0; dt < 4; ++dt) accO[dt] = MFMA32(pa0, vb[dt], accO[dt]);
#pragma unroll
    for (int dt = 0; dt < 4; ++dt) accO[dt] = MFMA32(pa1, vb[4 + dt], accO[dt]);
    acc = accn;
#pragma unroll
    for (int j = 0; j < 8; ++j) vb[j] = vbn[j];
  }

  // ---- 4-way O reduction in LDS ----
  __syncthreads();
#pragma unroll
  for (int ph = 0; ph < 4; ++ph) {
    if (wv == ph) {
#pragma unroll
      for (int dt = 0; dt < 4; ++dt) {
#pragma unroll
        for (int r = 0; r < 16; ++r) {
          const int q = (r & 3) + 8 * (r >> 2) + 4 * h2;
          R[q][dt * 32 + lq] += accO[dt][r];
        }
      }
    }
    __syncthreads();
  }
  {
    const int row = tid >> 3, c0 = (tid & 7) * 16;
    float* ob = Out + ((size_t)b * SS + q0 + row) * DD + c0;
#pragma unroll
    for (int j = 0; j < 4; ++j) nt_store4(&R[row][c0 + 4 * j], ob + 4 * j);
  }
}

// ---------------------------------------------------------------------------
extern "C" void kernel_launch(void* const* d_in, const int* in_sizes, int n_in,
                              void* d_out, int out_size, void* d_ws, size_t ws_size,
                              hipStream_t stream) {
  const float* Q = (const float*)d_in[0];
  const float* K = (const float*)d_in[1];
  const float* V = (const float*)d_in[2];
  float* out = (float*)d_out;
  float* W = out + (size_t)NQK;  // attn_weights region of d_out

  char* ws = (char*)d_ws;  // 12 MB used
  unsigned short* Qt = (unsigned short*)(ws);
  unsigned short* Kt = (unsigned short*)(ws + ((size_t)4 << 20));
  unsigned short* Vt = (unsigned short*)(ws + ((size_t)8 << 20));

  prep_kernel<<<dim3(64, 8, 3), 256, 0, stream>>>(Q, K, V, Qt, Kt, Vt);
  attn_kernel<<<512, 256, 0, stream>>>(Qt, Kt, Vt, W, out);
}